// Round 6
// baseline (718.283 us; speedup 1.0000x reference)
//
#include <hip/hip_runtime.h>
#include <hip/hip_fp16.h>

// SparseTransE scoring — R6: L3-resident fp16 normalized-entity table.
//
// Evidence chain:
//   R4 diagnostic: warm (cache-resident) re-run of the full gather+compute
//   pipeline costs 13us vs 272us cold => the kernel is cold-fetch-path bound
//   (random 1KB rows from a 512MB table at ~1TB/s effective; R2 proved more
//   software MLP doesn't help). On-chip random access is nearly free.
// Attack: make the randomly-accessed data L3-resident.
//   Phase A (normalize_f16_kernel): stream 512MB fp32 entity rows, normalize
//     (norm floored at EPS, fp32 math), write fp16 rows to d_ws. Table is
//     500K x 256 x 2B = 244MiB < 256MiB Infinity Cache -> resident.
//     Sequential R+W ~774MB at ~6.3TB/s ~= 125us.
//   Phase B (transe_score_f16_kernel): R1 structure, but h/t rows are 512B
//     fp16 loads from the L3-resident table (no norm butterflies — rows are
//     pre-normalized); relation rows stay fp32 from emb (1MB, L2-hot).
// Numerics: h-bar/t-bar stored fp16 (components <=~0.2) => score abs error
//   ~1e-3 on O(250) scores — far inside the tolerance fp32 variants passed.
// Fallback: if ws too small, R1 fused kernel (proven 602-606us).

#define EMB 256
#define EPS 1e-12f

typedef _Float16 half4 __attribute__((ext_vector_type(4)));

// ---------------- Phase A: normalized fp16 entity table (streaming) ----------
#define NRM_RPW 4

__global__ __launch_bounds__(256) void normalize_f16_kernel(
    const float* __restrict__ emb, _Float16* __restrict__ tab,
    const int* __restrict__ n_ent_ptr)
{
    const int wave = (blockIdx.x * blockDim.x + threadIdx.x) >> 6;
    const int lane = threadIdx.x & 63;
    const int n_ent = *n_ent_ptr;
    const int base = wave * NRM_RPW;
    if (base >= n_ent) return;

    float4 v[NRM_RPW];
    float s[NRM_RPW];
#pragma unroll
    for (int i = 0; i < NRM_RPW; ++i) {
        const int row = base + i;
        v[i] = make_float4(0.f, 0.f, 0.f, 0.f);
        if (row < n_ent)
            v[i] = ((const float4*)(emb + (size_t)row * EMB))[lane];
        s[i] = v[i].x * v[i].x + v[i].y * v[i].y + v[i].z * v[i].z + v[i].w * v[i].w;
    }
#pragma unroll
    for (int d = 32; d >= 1; d >>= 1)
#pragma unroll
        for (int i = 0; i < NRM_RPW; ++i)
            s[i] += __shfl_xor(s[i], d, 64);

#pragma unroll
    for (int i = 0; i < NRM_RPW; ++i) {
        const int row = base + i;
        if (row < n_ent) {
            const float inv = 1.0f / fmaxf(sqrtf(s[i]), EPS);
            half4 o;
            o.x = (_Float16)(v[i].x * inv);
            o.y = (_Float16)(v[i].y * inv);
            o.z = (_Float16)(v[i].z * inv);
            o.w = (_Float16)(v[i].w * inv);
            ((half4*)(tab + (size_t)row * EMB))[lane] = o;
        }
    }
}

// ---------------- Phase B: score from L3-resident fp16 table -----------------
#define SPW 4

__global__ __launch_bounds__(256) void transe_score_f16_kernel(
    const float* __restrict__ emb,
    const _Float16* __restrict__ tab,
    const int* __restrict__ pos_h, const int* __restrict__ pos_r, const int* __restrict__ pos_t,
    const int* __restrict__ neg_h, const int* __restrict__ neg_r, const int* __restrict__ neg_t,
    const int* __restrict__ n_ent_ptr,
    float* __restrict__ out, int B)
{
    const int wave = (blockIdx.x * blockDim.x + threadIdx.x) >> 6;
    const int lane = threadIdx.x & 63;
    const int base = wave * SPW;
    if (base >= 2 * B) return;

    const int n_ent = *n_ent_ptr;

    const int* __restrict__ hsrc;
    const int* __restrict__ rsrc;
    const int* __restrict__ tsrc;
    int off;
    if (base < B) { hsrc = pos_h; rsrc = pos_r; tsrc = pos_t; off = base; }
    else          { hsrc = neg_h; rsrc = neg_r; tsrc = neg_t; off = base - B; }

    const int4 hh = *(const int4*)(hsrc + off);
    const int4 rr = *(const int4*)(rsrc + off);
    const int4 tt = *(const int4*)(tsrc + off);

    const int hi[SPW] = {hh.x, hh.y, hh.z, hh.w};
    const int ri[SPW] = {rr.x, rr.y, rr.z, rr.w};
    const int ti[SPW] = {tt.x, tt.y, tt.z, tt.w};

    // 8 x 8B fp16 gathers (L3-resident table) + 4 x 16B fp32 relation loads
    // (L2-hot), all issued before use.
    half4  hv[SPW], tv[SPW];
    float4 rv[SPW];
#pragma unroll
    for (int s = 0; s < SPW; ++s) {
        hv[s] = ((const half4*)(tab + (size_t)hi[s] * EMB))[lane];
        tv[s] = ((const half4*)(tab + (size_t)ti[s] * EMB))[lane];
        rv[s] = ((const float4*)(emb + ((size_t)ri[s] + (size_t)n_ent) * EMB))[lane];
    }

    float sq[SPW];
#pragma unroll
    for (int s = 0; s < SPW; ++s) {
        const float vx = (float)hv[s].x + rv[s].x - (float)tv[s].x;
        const float vy = (float)hv[s].y + rv[s].y - (float)tv[s].y;
        const float vz = (float)hv[s].z + rv[s].z - (float)tv[s].z;
        const float vw = (float)hv[s].w + rv[s].w - (float)tv[s].w;
        sq[s] = vx * vx + vy * vy + vz * vz + vw * vw;
    }
#pragma unroll
    for (int d = 32; d >= 1; d >>= 1)
#pragma unroll
        for (int k = 0; k < SPW; ++k)
            sq[k] += __shfl_xor(sq[k], d, 64);

    if (lane == 0)
        *(float4*)(out + base) = make_float4(-sq[0], -sq[1], -sq[2], -sq[3]);
}

// ---------------- Fallback: R1 fused kernel (ws too small) --------------------
__global__ __launch_bounds__(256) void transe_score_fused_kernel(
    const float* __restrict__ emb,
    const int* __restrict__ pos_h, const int* __restrict__ pos_r, const int* __restrict__ pos_t,
    const int* __restrict__ neg_h, const int* __restrict__ neg_r, const int* __restrict__ neg_t,
    const int* __restrict__ n_ent_ptr,
    float* __restrict__ out, int B)
{
    const int wave = (blockIdx.x * blockDim.x + threadIdx.x) >> 6;
    const int lane = threadIdx.x & 63;
    const int base = wave * SPW;
    if (base >= 2 * B) return;

    const int n_ent = *n_ent_ptr;

    const int* __restrict__ hsrc;
    const int* __restrict__ rsrc;
    const int* __restrict__ tsrc;
    int off;
    if (base < B) { hsrc = pos_h; rsrc = pos_r; tsrc = pos_t; off = base; }
    else          { hsrc = neg_h; rsrc = neg_r; tsrc = neg_t; off = base - B; }

    const int4 hh = *(const int4*)(hsrc + off);
    const int4 rr = *(const int4*)(rsrc + off);
    const int4 tt = *(const int4*)(tsrc + off);

    const int hi[SPW] = {hh.x, hh.y, hh.z, hh.w};
    const int ri[SPW] = {rr.x, rr.y, rr.z, rr.w};
    const int ti[SPW] = {tt.x, tt.y, tt.z, tt.w};

    float4 hv[SPW], tv[SPW], rv[SPW];
#pragma unroll
    for (int s = 0; s < SPW; ++s) {
        hv[s] = ((const float4*)(emb + (size_t)hi[s] * EMB))[lane];
        tv[s] = ((const float4*)(emb + (size_t)ti[s] * EMB))[lane];
        rv[s] = ((const float4*)(emb + ((size_t)ri[s] + (size_t)n_ent) * EMB))[lane];
    }

    float red[2 * SPW];
#pragma unroll
    for (int s = 0; s < SPW; ++s) {
        red[s]       = hv[s].x * hv[s].x + hv[s].y * hv[s].y + hv[s].z * hv[s].z + hv[s].w * hv[s].w;
        red[SPW + s] = tv[s].x * tv[s].x + tv[s].y * tv[s].y + tv[s].z * tv[s].z + tv[s].w * tv[s].w;
    }
#pragma unroll
    for (int d = 32; d >= 1; d >>= 1) {
#pragma unroll
        for (int k = 0; k < 2 * SPW; ++k)
            red[k] += __shfl_xor(red[k], d, 64);
    }

    float sq[SPW];
#pragma unroll
    for (int s = 0; s < SPW; ++s) {
        const float inh = 1.0f / fmaxf(sqrtf(red[s]), EPS);
        const float itn = 1.0f / fmaxf(sqrtf(red[SPW + s]), EPS);
        const float vx = hv[s].x * inh + rv[s].x - tv[s].x * itn;
        const float vy = hv[s].y * inh + rv[s].y - tv[s].y * itn;
        const float vz = hv[s].z * inh + rv[s].z - tv[s].z * itn;
        const float vw = hv[s].w * inh + rv[s].w - tv[s].w * itn;
        sq[s] = vx * vx + vy * vy + vz * vz + vw * vw;
    }
#pragma unroll
    for (int d = 32; d >= 1; d >>= 1) {
#pragma unroll
        for (int k = 0; k < SPW; ++k)
            sq[k] += __shfl_xor(sq[k], d, 64);
    }

    if (lane == 0)
        *(float4*)(out + base) = make_float4(-sq[0], -sq[1], -sq[2], -sq[3]);
}

extern "C" void kernel_launch(void* const* d_in, const int* in_sizes, int n_in,
                              void* d_out, int out_size, void* d_ws, size_t ws_size,
                              hipStream_t stream) {
    const float* emb  = (const float*)d_in[0];
    const int* pos_h  = (const int*)d_in[1];
    const int* pos_r  = (const int*)d_in[2];
    const int* pos_t  = (const int*)d_in[3];
    const int* neg_h  = (const int*)d_in[4];
    const int* neg_r  = (const int*)d_in[5];
    const int* neg_t  = (const int*)d_in[6];
    const int* n_ent  = (const int*)d_in[7];
    float* out = (float*)d_out;

    const int B = in_sizes[1];                            // 65536
    const int total = 2 * B;                              // 131072 scores
    const size_t rows_total = (size_t)in_sizes[0] / EMB;  // n_ent + n_rel (host upper bound)

    const int waves_b = (total + SPW - 1) / SPW;
    const int grid_b  = (waves_b * 64 + 255) / 256;

    if (d_ws != nullptr && ws_size >= rows_total * EMB * sizeof(_Float16)) {
        _Float16* tab = (_Float16*)d_ws;

        const long long waves_a = ((long long)rows_total + NRM_RPW - 1) / NRM_RPW;
        const int grid_a = (int)((waves_a * 64 + 255) / 256);

        normalize_f16_kernel<<<grid_a, 256, 0, stream>>>(emb, tab, n_ent);
        transe_score_f16_kernel<<<grid_b, 256, 0, stream>>>(
            emb, tab, pos_h, pos_r, pos_t, neg_h, neg_r, neg_t, n_ent, out, B);
    } else {
        transe_score_fused_kernel<<<grid_b, 256, 0, stream>>>(
            emb, pos_h, pos_r, pos_t, neg_h, neg_r, neg_t, n_ent, out, B);
    }
}

// Round 8
// 645.843 us; speedup vs baseline: 1.1122x; 1.1122x over previous
//
#include <hip/hip_runtime.h>

// SparseTransE scoring — R7 (resubmit after broker timeout): t-sorted gather.
//
// Evidence chain (R2/R4/R6): random 1KB-row gather runs at a ~1 TB/s plateau
// invariant to bytes/row (fp32 vs fp16), load destination (VGPR vs LDS), and
// L3 residency (244MiB table resident => no change). Only XCD-local cache
// hits escape it (R4 warm re-gather: 13us vs 272us cold). The one untested
// axis is ACCESS ORDER — the same fabric does 6.3-6.4 TB/s when sequential.
// The cross-term h.t forces one random side per score; this build makes the
// t-side ascending via a 2048-bin counting sort (key = t>>8) and eats the
// random plateau only on the h-side (131K rows instead of 262K).
//
// Pipeline (all fp32; absmax should return to 1.0):
//   K0 zero 2048-bin histogram        (8 blocks)
//   K1 atomic histogram of t-keys     (512 blocks)
//   K2 exclusive scan, single block   (1 block x 1024)
//   K3 scatter triples into AoS recs  (512 blocks)  rec = {h, r, t, slot}
//   K4 score in sorted order (R1 math, SPW=4): t ascending, h random, r hot,
//      scalar scatter-store to out[slot].
// Fallback: R1 fused kernel if ws too small.
//
// Predicted: dur ~500-540us if ascending order restores DRAM efficiency on
// the t-side; ~640-660 if the plateau is order-invariant (theory killed).

#define EMB 256
#define EPS 1e-12f
#define SPW 4
#define NBINS 2048

// ---------------- K0: zero histogram ----------------
__global__ __launch_bounds__(256) void k0_zero_hist(int* __restrict__ hist)
{
    const int i = blockIdx.x * blockDim.x + threadIdx.x;
    if (i < NBINS) hist[i] = 0;
}

// ---------------- K1: histogram of t>>8 ----------------
__global__ __launch_bounds__(256) void k1_hist(
    const int* __restrict__ pos_t, const int* __restrict__ neg_t,
    int* __restrict__ hist, int B)
{
    const int i = blockIdx.x * blockDim.x + threadIdx.x;
    if (i >= 2 * B) return;
    const int t = (i < B) ? pos_t[i] : neg_t[i - B];
    int key = t >> 8; if (key > NBINS - 1) key = NBINS - 1;
    atomicAdd(&hist[key], 1);
}

// ---------------- K2: exclusive scan of 2048 bins (one block) ----------------
__global__ __launch_bounds__(1024) void k2_scan(int* __restrict__ hist)
{
    __shared__ int wt[16];
    const int tid  = threadIdx.x;          // 0..1023, owns bins 2t,2t+1
    const int lane = tid & 63;
    const int wid  = tid >> 6;

    const int a0 = hist[2 * tid];
    const int a1 = hist[2 * tid + 1];
    const int s  = a0 + a1;

    // wave-inclusive scan of s
    int v = s;
#pragma unroll
    for (int d = 1; d < 64; d <<= 1) {
        const int x = __shfl_up(v, d, 64);
        if (lane >= d) v += x;
    }
    if (lane == 63) wt[wid] = v;
    __syncthreads();
    if (wid == 0) {
        int w = (lane < 16) ? wt[lane] : 0;
        int vv = w;
#pragma unroll
        for (int d = 1; d < 16; d <<= 1) {
            const int x = __shfl_up(vv, d, 64);
            if (lane >= d) vv += x;
        }
        if (lane < 16) wt[lane] = vv - w;   // exclusive wave offset
    }
    __syncthreads();

    const int block_incl = v + wt[wid];
    const int e0 = block_incl - s;          // exclusive prefix for bin 2t
    hist[2 * tid]     = e0;
    hist[2 * tid + 1] = e0 + a0;
}

// ---------------- K3: scatter into sorted AoS records ----------------
__global__ __launch_bounds__(256) void k3_scatter(
    const int* __restrict__ pos_h, const int* __restrict__ pos_r, const int* __restrict__ pos_t,
    const int* __restrict__ neg_h, const int* __restrict__ neg_r, const int* __restrict__ neg_t,
    int* __restrict__ cursor, int4* __restrict__ rec, int B)
{
    const int i = blockIdx.x * blockDim.x + threadIdx.x;
    if (i >= 2 * B) return;
    int h, r, t;
    if (i < B) { h = pos_h[i]; r = pos_r[i]; t = pos_t[i]; }
    else       { h = neg_h[i - B]; r = neg_r[i - B]; t = neg_t[i - B]; }
    int key = t >> 8; if (key > NBINS - 1) key = NBINS - 1;
    const int dst = atomicAdd(&cursor[key], 1);
    rec[dst] = make_int4(h, r, t, i);       // slot = i (pos then neg layout)
}

// ---------------- K4: score in t-sorted order (R1 math) ----------------
__global__ __launch_bounds__(256) void k4_score_sorted(
    const float* __restrict__ emb,
    const int4* __restrict__ rec,
    const int* __restrict__ n_ent_ptr,
    float* __restrict__ out, int B)
{
    const int wave = (blockIdx.x * blockDim.x + threadIdx.x) >> 6;
    const int lane = threadIdx.x & 63;
    const int base = wave * SPW;
    if (base >= 2 * B) return;

    const int n_ent = *n_ent_ptr;

    int hi[SPW], ri[SPW], ti[SPW], sl[SPW];
#pragma unroll
    for (int s = 0; s < SPW; ++s) {
        const int4 q = rec[base + s];       // wave-uniform -> scalarizes
        hi[s] = q.x; ri[s] = q.y; ti[s] = q.z; sl[s] = q.w;
    }

    // Issue all 12 row loads before any use. t-rows ascending across waves,
    // h-rows random, r-rows L2-hot.
    float4 hv[SPW], tv[SPW], rv[SPW];
#pragma unroll
    for (int s = 0; s < SPW; ++s) {
        hv[s] = ((const float4*)(emb + (size_t)hi[s] * EMB))[lane];
        tv[s] = ((const float4*)(emb + (size_t)ti[s] * EMB))[lane];
        rv[s] = ((const float4*)(emb + ((size_t)ri[s] + (size_t)n_ent) * EMB))[lane];
    }

    float red[2 * SPW];
#pragma unroll
    for (int s = 0; s < SPW; ++s) {
        red[s]       = hv[s].x * hv[s].x + hv[s].y * hv[s].y + hv[s].z * hv[s].z + hv[s].w * hv[s].w;
        red[SPW + s] = tv[s].x * tv[s].x + tv[s].y * tv[s].y + tv[s].z * tv[s].z + tv[s].w * tv[s].w;
    }
#pragma unroll
    for (int d = 32; d >= 1; d >>= 1) {
#pragma unroll
        for (int k = 0; k < 2 * SPW; ++k)
            red[k] += __shfl_xor(red[k], d, 64);
    }

    float sq[SPW];
#pragma unroll
    for (int s = 0; s < SPW; ++s) {
        const float inh = 1.0f / fmaxf(sqrtf(red[s]), EPS);
        const float itn = 1.0f / fmaxf(sqrtf(red[SPW + s]), EPS);
        const float vx = hv[s].x * inh + rv[s].x - tv[s].x * itn;
        const float vy = hv[s].y * inh + rv[s].y - tv[s].y * itn;
        const float vz = hv[s].z * inh + rv[s].z - tv[s].z * itn;
        const float vw = hv[s].w * inh + rv[s].w - tv[s].w * itn;
        sq[s] = vx * vx + vy * vy + vz * vz + vw * vw;
    }
#pragma unroll
    for (int d = 32; d >= 1; d >>= 1) {
#pragma unroll
        for (int k = 0; k < SPW; ++k)
            sq[k] += __shfl_xor(sq[k], d, 64);
    }

    if (lane == 0) {
#pragma unroll
        for (int s = 0; s < SPW; ++s)
            out[sl[s]] = -sq[s];
    }
}

// ---------------- Fallback: R1 fused kernel (ws too small) --------------------
__global__ __launch_bounds__(256) void transe_score_fused_kernel(
    const float* __restrict__ emb,
    const int* __restrict__ pos_h, const int* __restrict__ pos_r, const int* __restrict__ pos_t,
    const int* __restrict__ neg_h, const int* __restrict__ neg_r, const int* __restrict__ neg_t,
    const int* __restrict__ n_ent_ptr,
    float* __restrict__ out, int B)
{
    const int wave = (blockIdx.x * blockDim.x + threadIdx.x) >> 6;
    const int lane = threadIdx.x & 63;
    const int base = wave * SPW;
    if (base >= 2 * B) return;

    const int n_ent = *n_ent_ptr;

    const int* __restrict__ hsrc;
    const int* __restrict__ rsrc;
    const int* __restrict__ tsrc;
    int off;
    if (base < B) { hsrc = pos_h; rsrc = pos_r; tsrc = pos_t; off = base; }
    else          { hsrc = neg_h; rsrc = neg_r; tsrc = neg_t; off = base - B; }

    const int4 hh = *(const int4*)(hsrc + off);
    const int4 rr = *(const int4*)(rsrc + off);
    const int4 tt = *(const int4*)(tsrc + off);

    const int hi[SPW] = {hh.x, hh.y, hh.z, hh.w};
    const int ri[SPW] = {rr.x, rr.y, rr.z, rr.w};
    const int ti[SPW] = {tt.x, tt.y, tt.z, tt.w};

    float4 hv[SPW], tv[SPW], rv[SPW];
#pragma unroll
    for (int s = 0; s < SPW; ++s) {
        hv[s] = ((const float4*)(emb + (size_t)hi[s] * EMB))[lane];
        tv[s] = ((const float4*)(emb + (size_t)ti[s] * EMB))[lane];
        rv[s] = ((const float4*)(emb + ((size_t)ri[s] + (size_t)n_ent) * EMB))[lane];
    }

    float red[2 * SPW];
#pragma unroll
    for (int s = 0; s < SPW; ++s) {
        red[s]       = hv[s].x * hv[s].x + hv[s].y * hv[s].y + hv[s].z * hv[s].z + hv[s].w * hv[s].w;
        red[SPW + s] = tv[s].x * tv[s].x + tv[s].y * tv[s].y + tv[s].z * tv[s].z + tv[s].w * tv[s].w;
    }
#pragma unroll
    for (int d = 32; d >= 1; d >>= 1) {
#pragma unroll
        for (int k = 0; k < 2 * SPW; ++k)
            red[k] += __shfl_xor(red[k], d, 64);
    }

    float sq[SPW];
#pragma unroll
    for (int s = 0; s < SPW; ++s) {
        const float inh = 1.0f / fmaxf(sqrtf(red[s]), EPS);
        const float itn = 1.0f / fmaxf(sqrtf(red[SPW + s]), EPS);
        const float vx = hv[s].x * inh + rv[s].x - tv[s].x * itn;
        const float vy = hv[s].y * inh + rv[s].y - tv[s].y * itn;
        const float vz = hv[s].z * inh + rv[s].z - tv[s].z * itn;
        const float vw = hv[s].w * inh + rv[s].w - tv[s].w * itn;
        sq[s] = vx * vx + vy * vy + vz * vz + vw * vw;
    }
#pragma unroll
    for (int d = 32; d >= 1; d >>= 1) {
#pragma unroll
        for (int k = 0; k < SPW; ++k)
            sq[k] += __shfl_xor(sq[k], d, 64);
    }

    if (lane == 0)
        *(float4*)(out + base) = make_float4(-sq[0], -sq[1], -sq[2], -sq[3]);
}

extern "C" void kernel_launch(void* const* d_in, const int* in_sizes, int n_in,
                              void* d_out, int out_size, void* d_ws, size_t ws_size,
                              hipStream_t stream) {
    const float* emb  = (const float*)d_in[0];
    const int* pos_h  = (const int*)d_in[1];
    const int* pos_r  = (const int*)d_in[2];
    const int* pos_t  = (const int*)d_in[3];
    const int* neg_h  = (const int*)d_in[4];
    const int* neg_r  = (const int*)d_in[5];
    const int* neg_t  = (const int*)d_in[6];
    const int* n_ent  = (const int*)d_in[7];
    float* out = (float*)d_out;

    const int B = in_sizes[1];               // 65536
    const int total = 2 * B;                 // 131072 scores

    // Workspace layout: [0,8KB) histogram/cursor; [64KB, 64KB+16B*total) AoS recs.
    const size_t need = 65536 + (size_t)total * sizeof(int4);

    const int waves = (total + SPW - 1) / SPW;
    const int grid4 = (waves * 64 + 255) / 256;

    if (d_ws != nullptr && ws_size >= need && (total & 3) == 0) {
        int*  hist = (int*)d_ws;
        int4* rec  = (int4*)((char*)d_ws + 65536);

        const int gridT = (total + 255) / 256;       // 512 blocks for 131072
        k0_zero_hist<<<(NBINS + 255) / 256, 256, 0, stream>>>(hist);
        k1_hist<<<gridT, 256, 0, stream>>>(pos_t, neg_t, hist, B);
        k2_scan<<<1, 1024, 0, stream>>>(hist);
        k3_scatter<<<gridT, 256, 0, stream>>>(pos_h, pos_r, pos_t,
                                              neg_h, neg_r, neg_t, hist, rec, B);
        k4_score_sorted<<<grid4, 256, 0, stream>>>(emb, rec, n_ent, out, B);
    } else {
        transe_score_fused_kernel<<<grid4, 256, 0, stream>>>(
            emb, pos_h, pos_r, pos_t, neg_h, neg_r, neg_t, n_ent, out, B);
    }
}